// Round 2
// baseline (3440.931 us; speedup 1.0000x reference)
//
#include <hip/hip_runtime.h>

#define Bsz  512
#define FEAT 2048
#define Hd   512
#define Vd   100
#define Td   200
#define Gd   2048   // 4*H interleaved gate columns: per 16-col group [r|z|i_n|h_n]

typedef __bf16 bf16;
typedef __bf16 bf16x8 __attribute__((ext_vector_type(8)));
typedef float  f32x4  __attribute__((ext_vector_type(4)));

// Static device storage. Rewritten every launch -> deterministic across replays.
__device__ bf16  g_hbuf[Td + 1][Bsz][Hd];   // h chain: [0]=h0, [t+1]=output of step t
__device__ bf16  g_wt0[Gd][Hd];             // step-0 weights   [gatecol][k]
__device__ bf16  g_wt1[Gd][Hd];             // steps>=1 weights [gatecol][k]
__device__ float g_bias0[Gd];
__device__ float g_bias1[Gd];
__device__ bf16  g_featbf[Bsz][FEAT];
__device__ bf16  g_whpt[Hd][FEAT];          // w_hp transposed: [n][k]
__device__ bf16  g_wprojt[112][Hd];         // w_proj transposed+padded: [v][k]
__device__ float g_gi0[3 * Hd];             // embed[SOS] @ w_ih.T + b_ih
__device__ unsigned g_bar[8 * 64];          // per-row-group barrier counters (stride 256B)

__device__ __forceinline__ float sigmoidf_(float x) {
  x = fminf(fmaxf(x, -30.f), 30.f);
  return 1.f / (1.f + __expf(-x));
}
__device__ __forceinline__ float tanhf_(float x) {
  x = fminf(fmaxf(x, -15.f), 15.f);
  float e = __expf(2.f * x);
  return (e - 1.f) / (e + 1.f);
}

// Monotonic-counter barrier among the 32 blocks of row-group bx.
// Device-scope fences so correctness never depends on XCD placement (G16).
__device__ __forceinline__ void group_barrier(int bx, unsigned target) {
  __syncthreads();
  if (threadIdx.x == 0) {
    __threadfence();  // release: make this block's h stores visible device-wide
    __hip_atomic_fetch_add(&g_bar[bx * 64], 1u, __ATOMIC_RELAXED, __HIP_MEMORY_SCOPE_AGENT);
    while (__hip_atomic_load(&g_bar[bx * 64], __ATOMIC_RELAXED, __HIP_MEMORY_SCOPE_AGENT) < target) {
      __builtin_amdgcn_s_sleep(1);
    }
    __threadfence();  // acquire: invalidate stale cached lines before next step's loads
  }
  __syncthreads();
}

// ---------- prep kernels ----------

__global__ void k_conv_feat(const float* feat) {
  int i = blockIdx.x * 256 + threadIdx.x;
  if (i < Bsz * FEAT) ((bf16*)g_featbf)[i] = (bf16)feat[i];
  if (blockIdx.x == 0 && threadIdx.x < 8) g_bar[threadIdx.x * 64] = 0u;  // reset barrier each replay
}

// gi0[j] = dot(embed[0], w_ih[j]) + b_ih[j] ; one wave per j, coalesced strided loads
__global__ void k_gi0(const float* embed, const float* w_ih, const float* b_ih) {
  int j = blockIdx.x;
  const float* wr = w_ih + (size_t)j * Hd;
  float s = 0.f;
  for (int k = threadIdx.x; k < Hd; k += 64) s += embed[k] * wr[k];
#pragma unroll
  for (int off = 32; off > 0; off >>= 1) s += __shfl_down(s, off);
  if (threadIdx.x == 0) g_gi0[j] = s + b_ih[j];
}

// gate col c: group g=c/64 (16 h-cols), f=(c>>4)&3 in {r,z,i_n,h_n}, j = g*16 + (c&15)
__global__ void k_build_wt1(const float* w_ih, const float* w_hh,
                            const float* b_ih, const float* b_hh) {
  int c = blockIdx.x;
  int j = (c >> 6) * 16 + (c & 15);
  int f = (c >> 4) & 3;
  const float* s1 = nullptr; const float* s2 = nullptr; float bias;
  if (f == 0)      { s1 = w_ih + (size_t)j * Hd;            s2 = w_hh + (size_t)j * Hd;            bias = b_ih[j] + b_hh[j]; }
  else if (f == 1) { s1 = w_ih + (size_t)(Hd + j) * Hd;     s2 = w_hh + (size_t)(Hd + j) * Hd;     bias = b_ih[Hd + j] + b_hh[Hd + j]; }
  else if (f == 2) { s1 = w_ih + (size_t)(2 * Hd + j) * Hd;                                        bias = b_ih[2 * Hd + j]; }
  else             { s1 = w_hh + (size_t)(2 * Hd + j) * Hd;                                        bias = b_hh[2 * Hd + j]; }
  for (int k = threadIdx.x; k < Hd; k += 256) {
    float v = s1[k] + (s2 ? s2[k] : 0.f);
    g_wt1[c][k] = (bf16)v;
  }
  if (threadIdx.x == 0) g_bias1[c] = bias;
}

__global__ void k_build_wt0(const float* w_hh, const float* b_hh) {
  int c = blockIdx.x;
  int j = (c >> 6) * 16 + (c & 15);
  int f = (c >> 4) & 3;
  const float* s1 = nullptr; float bias;
  if (f == 0)      { s1 = w_hh + (size_t)j * Hd;            bias = g_gi0[j] + b_hh[j]; }
  else if (f == 1) { s1 = w_hh + (size_t)(Hd + j) * Hd;     bias = g_gi0[Hd + j] + b_hh[Hd + j]; }
  else if (f == 2) {                                        bias = g_gi0[2 * Hd + j]; }  // i_n const at t=0
  else             { s1 = w_hh + (size_t)(2 * Hd + j) * Hd; bias = b_hh[2 * Hd + j]; }
  for (int k = threadIdx.x; k < Hd; k += 256)
    g_wt0[c][k] = (bf16)(s1 ? s1[k] : 0.f);
  if (threadIdx.x == 0) g_bias0[c] = bias;
}

__global__ void k_build_whpt(const float* w_hp) {
  int n = blockIdx.x;
  for (int k = threadIdx.x; k < FEAT; k += 256)
    g_whpt[n][k] = (bf16)w_hp[(size_t)k * Hd + n];
}

__global__ void k_build_wprojt(const float* w_proj) {
  int v = blockIdx.x;  // 0..111
  for (int k = threadIdx.x; k < Hd; k += 256)
    g_wprojt[v][k] = (bf16)(v < Vd ? w_proj[(size_t)k * Vd + v] : 0.f);
}

// ---------- persistent kernel: h0 + all 200 GRU steps ----------
// 256 blocks (1/CU), 256 threads (4 waves, 1 wave/SIMD -> up to 512 VGPR/wave).
// bx = bid&7 : 64-row batch group (XCD-affine under round-robin dispatch).
// gy = bid>>3: 16-h-col group (64 interleaved gate cols).
// Wave w: rows bx*64+w*16..+16. Weights for steps>=1 persist in 256 VGPRs/lane.
// Rows are independent across groups -> barrier only among the 32 blocks of bx.
__global__ __launch_bounds__(256, 1) void k_gru_seq(const float* b_hp) {
  const int bid = blockIdx.x;
  const int bx = bid & 7;
  const int gy = bid >> 3;
  const int w = threadIdx.x >> 6, l = threadIdx.x & 63;
  const int m = l & 15;
  const int ksub = (l >> 4) * 8;
  const int colb = gy * 64;
  const int arow = bx * 64 + w * 16 + m;
  const int orow = bx * 64 + w * 16 + (l >> 4) * 4;
  const int hcol = gy * 16 + m;

  // persistent B-fragments for steps >= 1 (4 gates x 16 k-chunks = 256 VGPR)
  bf16x8 B[64];
#pragma unroll
  for (int f = 0; f < 4; f++)
#pragma unroll
    for (int k0 = 0; k0 < 16; k0++)
      B[f * 16 + k0] = *(const bf16x8*)&g_wt1[colb + f * 16 + m][k0 * 32 + ksub];

  float b0v[4], b1v[4];
#pragma unroll
  for (int f = 0; f < 4; f++) {
    b0v[f] = g_bias0[colb + f * 16 + m];
    b1v[f] = g_bias1[colb + f * 16 + m];
  }

  // ---- h0 = feat @ w_hp + b_hp (this wave: 16 rows x 16 cols, K=2048) ----
  float hcarry[4];  // this block's own h values, carried in registers
  {
    f32x4 acc = {0.f, 0.f, 0.f, 0.f};
#pragma unroll 4
    for (int k0 = 0; k0 < FEAT; k0 += 32) {
      bf16x8 a = *(const bf16x8*)&g_featbf[arow][k0 + ksub];
      bf16x8 b = *(const bf16x8*)&g_whpt[hcol][k0 + ksub];
      acc = __builtin_amdgcn_mfma_f32_16x16x32_bf16(a, b, acc, 0, 0, 0);
    }
    float bhp = b_hp[hcol];
#pragma unroll
    for (int i = 0; i < 4; i++) {
      bf16 hv = (bf16)(acc[i] + bhp);
      g_hbuf[0][orow + i][hcol] = hv;
      hcarry[i] = (float)hv;
    }
  }

  unsigned phase = 1;
  group_barrier(bx, 32u * phase);  // h0 complete across row-group

  for (int t = 0; t < Td; t++) {
    // prefetch this wave's A-slice of h[t] (16 rows x 512 k), 16 x 16B/lane
    bf16x8 a[16];
    const bf16* Ap = &g_hbuf[t][arow][ksub];
#pragma unroll
    for (int k0 = 0; k0 < 16; k0++) a[k0] = *(const bf16x8*)(Ap + k0 * 32);

    f32x4 acc[4];
#pragma unroll
    for (int f = 0; f < 4; f++) {
      float bv = (t == 0) ? b0v[f] : b1v[f];
      acc[f] = (f32x4){bv, bv, bv, bv};
    }

    if (t == 0) {  // step 0 uses the wt0 weight set (read from L2 once)
#pragma unroll
      for (int k0 = 0; k0 < 16; k0++)
#pragma unroll
        for (int f = 0; f < 4; f++) {
          bf16x8 b = *(const bf16x8*)&g_wt0[colb + f * 16 + m][k0 * 32 + ksub];
          acc[f] = __builtin_amdgcn_mfma_f32_16x16x32_bf16(a[k0], b, acc[f], 0, 0, 0);
        }
    } else {
#pragma unroll
      for (int k0 = 0; k0 < 16; k0++)
#pragma unroll
        for (int f = 0; f < 4; f++)
          acc[f] = __builtin_amdgcn_mfma_f32_16x16x32_bf16(a[k0], B[f * 16 + k0], acc[f], 0, 0, 0);
    }

    // fused GRU epilogue: acc = r,z,i_n,h_n (biases folded in)
#pragma unroll
    for (int i = 0; i < 4; i++) {
      float r = sigmoidf_(acc[0][i]);
      float z = sigmoidf_(acc[1][i]);
      float n = tanhf_(acc[2][i] + r * acc[3][i]);
      float hn = (1.f - z) * n + z * hcarry[i];
      bf16 hv = (bf16)hn;
      g_hbuf[t + 1][orow + i][hcol] = hv;
      hcarry[i] = (float)hv;
    }

    if (t < Td - 1) {
      ++phase;
      group_barrier(bx, 32u * phase);
    }
  }
}

// ---------- projection: out[b][v][t] = sum_k h[t+1][b][k] * w_proj[k][v] + b_proj[v] ----------
// One wave per (b, t-tile): grid (512,13). High occupancy hides scattered B-loads.
__global__ __launch_bounds__(64) void k_proj(const float* b_proj, float* out) {
  int b = blockIdx.x;
  int tt = blockIdx.y;  // 0..12
  int l = threadIdx.x;
  int m = l & 15, ksub = (l >> 4) * 8;
  int tcol = tt * 16 + m;
  int trow = (tcol < Td ? tcol : Td - 1) + 1;  // clamp pad cols (masked on store)

  f32x4 acc[7];
#pragma unroll
  for (int f = 0; f < 7; f++)
#pragma unroll
    for (int i = 0; i < 4; i++) {
      int v = f * 16 + (l >> 4) * 4 + i;
      acc[f][i] = (v < Vd) ? b_proj[v] : 0.f;
    }

  const bf16* Bp = &g_hbuf[trow][b][ksub];
#pragma unroll 4
  for (int k0 = 0; k0 < Hd; k0 += 32) {
    bf16x8 bfrag = *(const bf16x8*)(Bp + k0);
#pragma unroll
    for (int f = 0; f < 7; f++) {
      bf16x8 afrag = *(const bf16x8*)&g_wprojt[f * 16 + m][k0 + ksub];
      acc[f] = __builtin_amdgcn_mfma_f32_16x16x32_bf16(afrag, bfrag, acc[f], 0, 0, 0);
    }
  }

  if (tcol < Td) {
#pragma unroll
    for (int f = 0; f < 7; f++)
#pragma unroll
      for (int i = 0; i < 4; i++) {
        int v = f * 16 + (l >> 4) * 4 + i;
        if (v < Vd) out[((size_t)b * Vd + v) * Td + tcol] = acc[f][i];
      }
  }
}

// ---------- launch ----------
extern "C" void kernel_launch(void* const* d_in, const int* in_sizes, int n_in,
                              void* d_out, int out_size, void* d_ws, size_t ws_size,
                              hipStream_t stream) {
  const float* feat   = (const float*)d_in[0];
  const float* w_hp   = (const float*)d_in[1];
  const float* b_hp   = (const float*)d_in[2];
  const float* embed  = (const float*)d_in[3];
  const float* w_ih   = (const float*)d_in[4];
  const float* w_hh   = (const float*)d_in[5];
  const float* b_ih   = (const float*)d_in[6];
  const float* b_hh   = (const float*)d_in[7];
  const float* w_proj = (const float*)d_in[8];
  const float* b_proj = (const float*)d_in[9];
  float* out = (float*)d_out;

  hipLaunchKernelGGL(k_conv_feat, dim3((Bsz * FEAT) / 256), dim3(256), 0, stream, feat);
  hipLaunchKernelGGL(k_gi0, dim3(3 * Hd), dim3(64), 0, stream, embed, w_ih, b_ih);
  hipLaunchKernelGGL(k_build_wt1, dim3(Gd), dim3(256), 0, stream, w_ih, w_hh, b_ih, b_hh);
  hipLaunchKernelGGL(k_build_wt0, dim3(Gd), dim3(256), 0, stream, w_hh, b_hh);
  hipLaunchKernelGGL(k_build_whpt, dim3(Hd), dim3(256), 0, stream, w_hp);
  hipLaunchKernelGGL(k_build_wprojt, dim3(112), dim3(256), 0, stream, w_proj);
  hipLaunchKernelGGL(k_gru_seq, dim3(256), dim3(256), 0, stream, b_hp);
  hipLaunchKernelGGL(k_proj, dim3(Bsz, 13), dim3(64), 0, stream, b_proj, out);
}

// Round 3
// 1100.542 us; speedup vs baseline: 3.1266x; 3.1266x over previous
//
#include <hip/hip_runtime.h>

#define Bsz  512
#define FEAT 2048
#define Hd   512
#define Vd   100
#define Td   200
#define Gd   2048   // 4*H interleaved gate columns: per 16-col group [r|z|i_n|h_n]

typedef __bf16 bf16;
typedef __bf16 bf16x8 __attribute__((ext_vector_type(8)));
typedef float  f32x4  __attribute__((ext_vector_type(4)));

// Static device storage. Rewritten every launch -> deterministic across replays.
__device__ bf16  g_hbuf[Td + 1][Bsz][Hd];   // h chain: [0]=h0, [t+1]=output of step t
__device__ bf16  g_wt0[Gd][Hd];             // step-0 weights   [gatecol][k]
__device__ bf16  g_wt1[Gd][Hd];             // steps>=1 weights [gatecol][k]
__device__ float g_bias0[Gd];
__device__ float g_bias1[Gd];
__device__ bf16  g_featbf[Bsz][FEAT];
__device__ bf16  g_whpt[Hd][FEAT];          // w_hp transposed: [n][k]
__device__ bf16  g_wprojt[112][Hd];         // w_proj transposed+padded: [v][k]
__device__ float g_gi0[3 * Hd];             // embed[SOS] @ w_ih.T + b_ih
__device__ unsigned g_flags[8][32];         // [rowgroup][colgroup] phase flags

// ---------- device-coherent (L2-bypass, sc0 sc1) access helpers ----------
// h data and flags NEVER live in L2 -> the inter-block barrier needs no
// writeback/invalidate; placement-independent correctness (G16).

template <int OFF>
__device__ __forceinline__ bf16x8 ld_b16x8_cohere(const void* p) {
  bf16x8 r;
  asm volatile("global_load_dwordx4 %0, %1, off offset:%2 sc0 sc1"
               : "=&v"(r) : "v"(p), "i"(OFF) : "memory");
  return r;
}
template <int OFF>
__device__ __forceinline__ void st_u16_cohere(void* p, unsigned short v) {
  asm volatile("global_store_short %0, %1, off offset:%2 sc0 sc1"
               :: "v"(p), "v"(v), "i"(OFF) : "memory");
}
__device__ __forceinline__ void st_u32_cohere(void* p, unsigned v) {
  asm volatile("global_store_dword %0, %1, off sc0 sc1" :: "v"(p), "v"(v) : "memory");
}
__device__ __forceinline__ unsigned ld_u32_cohere(const void* p) {
  unsigned r;
  asm volatile("global_load_dword %0, %1, off sc0 sc1\n\ts_waitcnt vmcnt(0)"
               : "=&v"(r) : "v"(p) : "memory");
  return r;
}
__device__ __forceinline__ void wait_vm0() { asm volatile("s_waitcnt vmcnt(0)" ::: "memory"); }
__device__ __forceinline__ void wait_vm8() { asm volatile("s_waitcnt vmcnt(8)" ::: "memory"); }

#define LDA16(arr, base) do {                                                   \
  arr[0]  = ld_b16x8_cohere<0>(base);   arr[1]  = ld_b16x8_cohere<64>(base);    \
  arr[2]  = ld_b16x8_cohere<128>(base); arr[3]  = ld_b16x8_cohere<192>(base);   \
  arr[4]  = ld_b16x8_cohere<256>(base); arr[5]  = ld_b16x8_cohere<320>(base);   \
  arr[6]  = ld_b16x8_cohere<384>(base); arr[7]  = ld_b16x8_cohere<448>(base);   \
  arr[8]  = ld_b16x8_cohere<512>(base); arr[9]  = ld_b16x8_cohere<576>(base);   \
  arr[10] = ld_b16x8_cohere<640>(base); arr[11] = ld_b16x8_cohere<704>(base);   \
  arr[12] = ld_b16x8_cohere<768>(base); arr[13] = ld_b16x8_cohere<832>(base);   \
  arr[14] = ld_b16x8_cohere<896>(base); arr[15] = ld_b16x8_cohere<960>(base);   \
} while (0)

__device__ __forceinline__ float sigmoidf_(float x) {
  x = fminf(fmaxf(x, -30.f), 30.f);
  return 1.f / (1.f + __expf(-x));
}
__device__ __forceinline__ float tanhf_(float x) {
  x = fminf(fmaxf(x, -15.f), 15.f);
  float e = __expf(2.f * x);
  return (e - 1.f) / (e + 1.f);
}

// Flag-array barrier among the 32 col-blocks of row-group rg.
// Caller has already issued its h stores (sc0 sc1). No atomic RMW, no fences:
// release = vmcnt(0) drain (stores at coherence point), flags polled at L3.
__device__ __forceinline__ void group_barrier(int rg, int cg, unsigned phase) {
  wait_vm0();          // this wave's h stores are at the coherence point
  __syncthreads();     // all 4 waves drained
  if (threadIdx.x == 0) st_u32_cohere(&g_flags[rg][cg], phase);
  if (threadIdx.x < 64) {
    const unsigned* fp = &g_flags[rg][threadIdx.x & 31];
    while (ld_u32_cohere(fp) < phase) __builtin_amdgcn_s_sleep(1);
  }
  __syncthreads();
}

// ---------- prep kernels ----------

__global__ void k_conv_feat(const float* feat) {
  int i = blockIdx.x * 256 + threadIdx.x;
  if (i < Bsz * FEAT) ((bf16*)g_featbf)[i] = (bf16)feat[i];
  if (blockIdx.x == 0) ((unsigned*)g_flags)[threadIdx.x] = 0u;  // reset 8*32 flags each replay
}

__global__ void k_gi0(const float* embed, const float* w_ih, const float* b_ih) {
  int j = blockIdx.x;
  const float* wr = w_ih + (size_t)j * Hd;
  float s = 0.f;
  for (int k = threadIdx.x; k < Hd; k += 64) s += embed[k] * wr[k];
#pragma unroll
  for (int off = 32; off > 0; off >>= 1) s += __shfl_down(s, off);
  if (threadIdx.x == 0) g_gi0[j] = s + b_ih[j];
}

// gate col c: group g=c/64 (16 h-cols), f=(c>>4)&3 in {r,z,i_n,h_n}, j = g*16 + (c&15)
__global__ void k_build_wt1(const float* w_ih, const float* w_hh,
                            const float* b_ih, const float* b_hh) {
  int c = blockIdx.x;
  int j = (c >> 6) * 16 + (c & 15);
  int f = (c >> 4) & 3;
  const float* s1 = nullptr; const float* s2 = nullptr; float bias;
  if (f == 0)      { s1 = w_ih + (size_t)j * Hd;            s2 = w_hh + (size_t)j * Hd;            bias = b_ih[j] + b_hh[j]; }
  else if (f == 1) { s1 = w_ih + (size_t)(Hd + j) * Hd;     s2 = w_hh + (size_t)(Hd + j) * Hd;     bias = b_ih[Hd + j] + b_hh[Hd + j]; }
  else if (f == 2) { s1 = w_ih + (size_t)(2 * Hd + j) * Hd;                                        bias = b_ih[2 * Hd + j]; }
  else             { s1 = w_hh + (size_t)(2 * Hd + j) * Hd;                                        bias = b_hh[2 * Hd + j]; }
  for (int k = threadIdx.x; k < Hd; k += 256) {
    float v = s1[k] + (s2 ? s2[k] : 0.f);
    g_wt1[c][k] = (bf16)v;
  }
  if (threadIdx.x == 0) g_bias1[c] = bias;
}

__global__ void k_build_wt0(const float* w_hh, const float* b_hh) {
  int c = blockIdx.x;
  int j = (c >> 6) * 16 + (c & 15);
  int f = (c >> 4) & 3;
  const float* s1 = nullptr; float bias;
  if (f == 0)      { s1 = w_hh + (size_t)j * Hd;            bias = g_gi0[j] + b_hh[j]; }
  else if (f == 1) { s1 = w_hh + (size_t)(Hd + j) * Hd;     bias = g_gi0[Hd + j] + b_hh[Hd + j]; }
  else if (f == 2) {                                        bias = g_gi0[2 * Hd + j]; }
  else             { s1 = w_hh + (size_t)(2 * Hd + j) * Hd; bias = b_hh[2 * Hd + j]; }
  for (int k = threadIdx.x; k < Hd; k += 256)
    g_wt0[c][k] = (bf16)(s1 ? s1[k] : 0.f);
  if (threadIdx.x == 0) g_bias0[c] = bias;
}

__global__ void k_build_whpt(const float* w_hp) {
  int n = blockIdx.x;
  for (int k = threadIdx.x; k < FEAT; k += 256)
    g_whpt[n][k] = (bf16)w_hp[(size_t)k * Hd + n];
}

__global__ void k_build_wprojt(const float* w_proj) {
  int v = blockIdx.x;  // 0..111
  for (int k = threadIdx.x; k < Hd; k += 256)
    g_wprojt[v][k] = (bf16)(v < Vd ? w_proj[(size_t)k * Vd + v] : 0.f);
}

// ---------- persistent kernel: h0 + all 200 GRU steps ----------
// 256 blocks (1/CU), 256 threads. rg=bid&7: 64-row batch group; cg=bid>>3: 16
// h-col group. Steps>=1 weights persist in VGPR/AGPR. Barrier among the 32
// blocks of rg only; h exchanged through the coherence point (sc0 sc1).
__global__ __launch_bounds__(256, 1) void k_gru_seq(const float* b_hp) {
  const int bid = blockIdx.x;
  const int rg = bid & 7;
  const int cg = bid >> 3;
  const int w = threadIdx.x >> 6, l = threadIdx.x & 63;
  const int m = l & 15;
  const int ksub = (l >> 4) * 8;
  const int colb = cg * 64;
  const int arow = rg * 64 + w * 16 + m;
  const int orow = rg * 64 + w * 16 + (l >> 4) * 4;
  const int hcol = cg * 16 + m;

  // persistent B-fragments for steps >= 1 (4 gates x 16 k-chunks)
  bf16x8 Bw[64];
#pragma unroll
  for (int f = 0; f < 4; f++)
#pragma unroll
    for (int k0 = 0; k0 < 16; k0++)
      Bw[f * 16 + k0] = *(const bf16x8*)&g_wt1[colb + f * 16 + m][k0 * 32 + ksub];

  float b0v[4], b1v[4];
#pragma unroll
  for (int f = 0; f < 4; f++) {
    b0v[f] = g_bias0[colb + f * 16 + m];
    b1v[f] = g_bias1[colb + f * 16 + m];
  }

  // ---- h0 = feat @ w_hp + b_hp ----
  float hcarry[4];
  {
    f32x4 acc = {0.f, 0.f, 0.f, 0.f};
#pragma unroll 4
    for (int k0 = 0; k0 < FEAT; k0 += 32) {
      bf16x8 a = *(const bf16x8*)&g_featbf[arow][k0 + ksub];
      bf16x8 b = *(const bf16x8*)&g_whpt[hcol][k0 + ksub];
      acc = __builtin_amdgcn_mfma_f32_16x16x32_bf16(a, b, acc, 0, 0, 0);
    }
    float bhp = b_hp[hcol];
    char* pb = (char*)&g_hbuf[0][orow][hcol];
    unsigned short us[4];
#pragma unroll
    for (int i = 0; i < 4; i++) {
      bf16 hv = (bf16)(acc[i] + bhp);
      hcarry[i] = (float)hv;
      us[i] = __builtin_bit_cast(unsigned short, hv);
    }
    st_u16_cohere<0>(pb, us[0]);    st_u16_cohere<1024>(pb, us[1]);
    st_u16_cohere<2048>(pb, us[2]); st_u16_cohere<3072>(pb, us[3]);
  }

  group_barrier(rg, cg, 1u);  // h0 complete across row-group

  for (int t = 0; t < Td; t++) {
    // this wave's A-slice of h[t]: 16 rows x 512 k, L2-bypass loads
    bf16x8 a[16];
    const char* Ap = (const char*)&g_hbuf[t][arow][ksub];
    LDA16(a, Ap);

    f32x4 acc[4];
#pragma unroll
    for (int f = 0; f < 4; f++) {
      float bv = (t == 0) ? b0v[f] : b1v[f];
      acc[f] = (f32x4){bv, bv, bv, bv};
    }

    if (t == 0) {  // step 0 uses the wt0 weight set (normal cached loads, once)
      wait_vm0(); __builtin_amdgcn_sched_barrier(0);
#pragma unroll
      for (int k0 = 0; k0 < 16; k0++)
#pragma unroll
        for (int f = 0; f < 4; f++) {
          bf16x8 b = *(const bf16x8*)&g_wt0[colb + f * 16 + m][k0 * 32 + ksub];
          acc[f] = __builtin_amdgcn_mfma_f32_16x16x32_bf16(a[k0], b, acc[f], 0, 0, 0);
        }
    } else {
      wait_vm8(); __builtin_amdgcn_sched_barrier(0);   // first 8 chunks landed
#pragma unroll
      for (int k0 = 0; k0 < 8; k0++)
#pragma unroll
        for (int f = 0; f < 4; f++)
          acc[f] = __builtin_amdgcn_mfma_f32_16x16x32_bf16(a[k0], Bw[f * 16 + k0], acc[f], 0, 0, 0);
      wait_vm0(); __builtin_amdgcn_sched_barrier(0);
#pragma unroll
      for (int k0 = 8; k0 < 16; k0++)
#pragma unroll
        for (int f = 0; f < 4; f++)
          acc[f] = __builtin_amdgcn_mfma_f32_16x16x32_bf16(a[k0], Bw[f * 16 + k0], acc[f], 0, 0, 0);
    }

    // fused GRU epilogue: acc = r,z,i_n,h_n (biases folded in)
    char* pb = (char*)&g_hbuf[t + 1][orow][hcol];
    unsigned short us[4];
#pragma unroll
    for (int i = 0; i < 4; i++) {
      float r = sigmoidf_(acc[0][i]);
      float z = sigmoidf_(acc[1][i]);
      float n = tanhf_(acc[2][i] + r * acc[3][i]);
      float hn = (1.f - z) * n + z * hcarry[i];
      bf16 hv = (bf16)hn;
      hcarry[i] = (float)hv;
      us[i] = __builtin_bit_cast(unsigned short, hv);
    }
    st_u16_cohere<0>(pb, us[0]);    st_u16_cohere<1024>(pb, us[1]);
    st_u16_cohere<2048>(pb, us[2]); st_u16_cohere<3072>(pb, us[3]);

    if (t < Td - 1) group_barrier(rg, cg, (unsigned)(t + 2));
  }
  wait_vm0();  // h[200] at coherence point before kernel end
}

// ---------- projection: out[b][v][t] = sum_k h[t+1][b][k] * w_proj[k][v] + b_proj[v] ----------
__global__ __launch_bounds__(64) void k_proj(const float* b_proj, float* out) {
  int b = blockIdx.x;
  int tt = blockIdx.y;  // 0..12
  int l = threadIdx.x;
  int m = l & 15, ksub = (l >> 4) * 8;
  int tcol = tt * 16 + m;
  int trow = (tcol < Td ? tcol : Td - 1) + 1;  // clamp pad cols (masked on store)

  f32x4 acc[7];
#pragma unroll
  for (int f = 0; f < 7; f++)
#pragma unroll
    for (int i = 0; i < 4; i++) {
      int v = f * 16 + (l >> 4) * 4 + i;
      acc[f][i] = (v < Vd) ? b_proj[v] : 0.f;
    }

  // h rows are read exactly once -> bypass L2 (also guarantees visibility of
  // gru_seq's sc0sc1 stores without relying on inter-kernel cache maintenance)
  bf16x8 bb[16];
  const char* Bp = (const char*)&g_hbuf[trow][b][ksub];
  LDA16(bb, Bp);
  wait_vm0(); __builtin_amdgcn_sched_barrier(0);

#pragma unroll
  for (int k0 = 0; k0 < 16; k0++)
#pragma unroll
    for (int f = 0; f < 7; f++) {
      bf16x8 afrag = *(const bf16x8*)&g_wprojt[f * 16 + m][k0 * 32 + ksub];
      acc[f] = __builtin_amdgcn_mfma_f32_16x16x32_bf16(afrag, bb[k0], acc[f], 0, 0, 0);
    }

  if (tcol < Td) {
#pragma unroll
    for (int f = 0; f < 7; f++)
#pragma unroll
      for (int i = 0; i < 4; i++) {
        int v = f * 16 + (l >> 4) * 4 + i;
        if (v < Vd) out[((size_t)b * Vd + v) * Td + tcol] = acc[f][i];
      }
  }
}

// ---------- launch ----------
extern "C" void kernel_launch(void* const* d_in, const int* in_sizes, int n_in,
                              void* d_out, int out_size, void* d_ws, size_t ws_size,
                              hipStream_t stream) {
  const float* feat   = (const float*)d_in[0];
  const float* w_hp   = (const float*)d_in[1];
  const float* b_hp   = (const float*)d_in[2];
  const float* embed  = (const float*)d_in[3];
  const float* w_ih   = (const float*)d_in[4];
  const float* w_hh   = (const float*)d_in[5];
  const float* b_ih   = (const float*)d_in[6];
  const float* b_hh   = (const float*)d_in[7];
  const float* w_proj = (const float*)d_in[8];
  const float* b_proj = (const float*)d_in[9];
  float* out = (float*)d_out;

  hipLaunchKernelGGL(k_conv_feat, dim3((Bsz * FEAT) / 256), dim3(256), 0, stream, feat);
  hipLaunchKernelGGL(k_gi0, dim3(3 * Hd), dim3(64), 0, stream, embed, w_ih, b_ih);
  hipLaunchKernelGGL(k_build_wt1, dim3(Gd), dim3(256), 0, stream, w_ih, w_hh, b_ih, b_hh);
  hipLaunchKernelGGL(k_build_wt0, dim3(Gd), dim3(256), 0, stream, w_hh, b_hh);
  hipLaunchKernelGGL(k_build_whpt, dim3(Hd), dim3(256), 0, stream, w_hp);
  hipLaunchKernelGGL(k_build_wprojt, dim3(112), dim3(256), 0, stream, w_proj);
  hipLaunchKernelGGL(k_gru_seq, dim3(256), dim3(256), 0, stream, b_hp);
  hipLaunchKernelGGL(k_proj, dim3(Bsz, 13), dim3(64), 0, stream, b_proj, out);
}